// Round 1
// baseline (489.730 us; speedup 1.0000x reference)
//
#include <hip/hip_runtime.h>

// Problem constants (B=4, S=4096, D=1024, H=16, dh=64, WIN=256, STRIDE=128, nw=31)
#define SEQ 4096
#define DIM 1024
#define NWIN 31
#define NHEAD 16

typedef __attribute__((ext_vector_type(8))) short bf16x8;
typedef __attribute__((ext_vector_type(4))) float f32x4;

#define MFMA(a, b, c) __builtin_amdgcn_mfma_f32_16x16x32_bf16((a), (b), (c), 0, 0, 0)

__device__ __forceinline__ unsigned short f2bf(float f) {
  union { float f; unsigned u; } v; v.f = f;
  unsigned r = v.u + 0x7FFFu + ((v.u >> 16) & 1u);
  return (unsigned short)(r >> 16);
}
__device__ __forceinline__ float bf2f(unsigned short h) {
  union { unsigned u; float f; } v; v.u = ((unsigned)h) << 16;
  return v.f;
}

// async global->LDS, 16B per lane. LDS dest = wave-uniform base + lane*16.
__device__ __forceinline__ void gll16(const void* g, void* l) {
  __builtin_amdgcn_global_load_lds((const __attribute__((address_space(1))) unsigned*)g,
                                   (__attribute__((address_space(3))) unsigned*)l,
                                   16, 0, 0);
}

// ---------------- elementwise cast / sum ----------------

__global__ __launch_bounds__(256) void cast_x_k(const float* __restrict__ x,
                                                unsigned short* __restrict__ o) {
  size_t i = ((size_t)blockIdx.x * 256 + threadIdx.x) * 8;
  float4 a = *(const float4*)(x + i);
  float4 b = *(const float4*)(x + i + 4);
  union { unsigned short u[8]; uint4 v; } pk;
  pk.u[0] = f2bf(a.x); pk.u[1] = f2bf(a.y); pk.u[2] = f2bf(a.z); pk.u[3] = f2bf(a.w);
  pk.u[4] = f2bf(b.x); pk.u[5] = f2bf(b.y); pk.u[6] = f2bf(b.z); pk.u[7] = f2bf(b.w);
  *(uint4*)(o + i) = pk.v;
}

__global__ __launch_bounds__(256) void sum_ctx_k(const unsigned short* __restrict__ a,
                                                 const unsigned short* __restrict__ b,
                                                 unsigned short* __restrict__ o) {
  size_t i = ((size_t)blockIdx.x * 256 + threadIdx.x) * 8;
  union { unsigned short u[8]; uint4 v; } pa, pb, po;
  pa.v = *(const uint4*)(a + i);
  pb.v = *(const uint4*)(b + i);
#pragma unroll
  for (int j = 0; j < 8; ++j) po.u[j] = f2bf(bf2f(pa.u[j]) + bf2f(pb.u[j]));
  *(uint4*)(o + i) = po.v;
}

// ---------------- weight transpose + cast: Wt[n][k] = bf16(W[k][n]) ----------------

__global__ __launch_bounds__(256) void tcast_w_k(const float* __restrict__ W0, const float* __restrict__ W1,
                                                 const float* __restrict__ W2, const float* __restrict__ W3,
                                                 unsigned short* __restrict__ Wt3,
                                                 unsigned short* __restrict__ WoT) {
  __shared__ float tile[64][65];
  const int bid = blockIdx.x;
  const int mat = bid >> 8;
  const int t = bid & 255;
  const int tr = (t >> 4) * 64, tc = (t & 15) * 64;
  const float* W = (mat == 0) ? W0 : (mat == 1) ? W1 : (mat == 2) ? W2 : W3;
  unsigned short* out = (mat < 3) ? (Wt3 + (size_t)mat * 1024 * 1024) : WoT;
  const int tid = threadIdx.x;
  const int rr = tid >> 4, cc = (tid & 15) << 2;
#pragma unroll
  for (int i = 0; i < 4; ++i) {
    int r = i * 16 + rr;
    float4 v = *(const float4*)(W + (size_t)(tr + r) * DIM + tc + cc);
    tile[r][cc] = v.x; tile[r][cc + 1] = v.y; tile[r][cc + 2] = v.z; tile[r][cc + 3] = v.w;
  }
  __syncthreads();
#pragma unroll
  for (int i = 0; i < 4; ++i) {
    int orow = i * 16 + rr;
    union { unsigned short u[4]; uint2 v; } pk;
#pragma unroll
    for (int j = 0; j < 4; ++j) pk.u[j] = f2bf(tile[cc + j][orow]);
    *(uint2*)(out + (size_t)(tc + orow) * DIM + tr + cc) = pk.v;
  }
}

// ---------------- shared GEMM core: C[128x128] = A[128xK] * Bt[128xK]^T ----------------
// A row-major [M][K], Bt row-major [N][K], bf16. LDS tiles XOR-swizzled
// (chunk ^= row&7 in 16B units) so ds_read_b128 fragment loads are ~2-way.

__device__ __forceinline__ void gemm_tile_compute(const unsigned short* __restrict__ A,
                                                  const unsigned short* __restrict__ Bt,
                                                  int K, int m0, int n0,
                                                  unsigned short* Alds, unsigned short* Blds,
                                                  f32x4 acc[4][4], int tid) {
  const int lane = tid & 63;
  const int w = tid >> 6;
  const int srow = lane >> 3, schunk = lane & 7;
  const int sxor = (schunk ^ srow) * 8;  // element offset of the pre-swizzled 16B chunk
  char* Ac = (char*)Alds;
  char* Bc = (char*)Blds;
  const int wr = (w >> 1) * 64, wc = (w & 1) * 64;

  int aoff[4][2], boff[4][2];
#pragma unroll
  for (int t = 0; t < 4; ++t) {
    int ra = wr + t * 16 + (lane & 15);
    int rb = wc + t * 16 + (lane & 15);
#pragma unroll
    for (int kf = 0; kf < 2; ++kf) {
      aoff[t][kf] = ra * 128 + (((kf * 4 + (lane >> 4)) ^ (ra & 7)) << 4);
      boff[t][kf] = rb * 128 + (((kf * 4 + (lane >> 4)) ^ (rb & 7)) << 4);
    }
  }

  const int nk = K >> 6;
  for (int kb = 0; kb < nk; ++kb) {
    const unsigned short* Ag = A + (size_t)(m0 + w * 32 + srow) * K + kb * 64 + sxor;
    const unsigned short* Bg = Bt + (size_t)(n0 + w * 32 + srow) * K + kb * 64 + sxor;
#pragma unroll
    for (int j = 0; j < 4; ++j) {
      gll16(Ag + (size_t)j * 8 * K, Ac + (w * 32 + j * 8) * 128);
      gll16(Bg + (size_t)j * 8 * K, Bc + (w * 32 + j * 8) * 128);
    }
    __syncthreads();  // drains vmcnt: staged data visible
#pragma unroll
    for (int kf = 0; kf < 2; ++kf) {
      bf16x8 af[4], bfr[4];
#pragma unroll
      for (int t = 0; t < 4; ++t) af[t] = *(const bf16x8*)(Ac + aoff[t][kf]);
#pragma unroll
      for (int t = 0; t < 4; ++t) bfr[t] = *(const bf16x8*)(Bc + boff[t][kf]);
#pragma unroll
      for (int mt = 0; mt < 4; ++mt)
#pragma unroll
        for (int nt = 0; nt < 4; ++nt)
          acc[mt][nt] = MFMA(af[mt], bfr[nt], acc[mt][nt]);
    }
    __syncthreads();  // all reads done before next-stage overwrite
  }
}

// ---------------- GEMM 1: [Q|K|V] = Xb @ W, V written transposed ----------------

__global__ __launch_bounds__(256) void gemm_qkv_k(const unsigned short* __restrict__ Xb,
                                                  const unsigned short* __restrict__ Wt3,
                                                  unsigned short* __restrict__ Qb,
                                                  unsigned short* __restrict__ Kb,
                                                  unsigned short* __restrict__ Vt) {
  __shared__ unsigned short Alds[128 * 64];
  __shared__ unsigned short Blds[128 * 64];
  const int nwg = 3072;  // 128 m-tiles * 24 n-tiles
  const int wg = blockIdx.x;
  const int swz = (wg & 7) * (nwg >> 3) + (wg >> 3);  // XCD-aware (nwg % 8 == 0)
  const int mtile = swz / 24, ntile = swz % 24;       // n fast: A-panel L2 reuse
  const int m0 = mtile * 128, n0 = ntile * 128;

  f32x4 acc[4][4] = {};
  gemm_tile_compute(Xb, Wt3, DIM, m0, n0, Alds, Blds, acc, threadIdx.x);

  const int lane = threadIdx.x & 63, w = threadIdx.x >> 6;
  const int mg0 = m0 + (w >> 1) * 64, ng0 = n0 + (w & 1) * 64;
  if (n0 < 2048) {
    unsigned short* O = (n0 < 1024) ? Qb : Kb;
    const int nb = (n0 < 1024) ? 0 : 1024;
#pragma unroll
    for (int mt = 0; mt < 4; ++mt)
#pragma unroll
      for (int nt = 0; nt < 4; ++nt) {
        int ng = ng0 + nt * 16 + (lane & 15) - nb;
        int mg = mg0 + mt * 16 + ((lane >> 4) << 2);
#pragma unroll
        for (int r = 0; r < 4; ++r)
          O[(size_t)(mg + r) * DIM + ng] = f2bf(acc[mt][nt][r]);
      }
  } else {
    // V: store transposed Vt[d_global][m], so attention B-operand reads are contiguous in k
#pragma unroll
    for (int mt = 0; mt < 4; ++mt)
#pragma unroll
      for (int nt = 0; nt < 4; ++nt) {
        int ng = ng0 + nt * 16 + (lane & 15) - 2048;
        int mg = mg0 + mt * 16 + ((lane >> 4) << 2);
        union { unsigned short u[4]; uint2 v; } pk;
#pragma unroll
        for (int r = 0; r < 4; ++r) pk.u[r] = f2bf(acc[mt][nt][r]);
        *(uint2*)(Vt + (size_t)ng * (4 * SEQ) + mg) = pk.v;
      }
  }
}

// ---------------- GEMM 2: out = (ctxS @ Wo) * rowscale ----------------

__global__ __launch_bounds__(256) void gemm_out_k(const unsigned short* __restrict__ Cs,
                                                  const unsigned short* __restrict__ WoT,
                                                  float* __restrict__ out) {
  __shared__ unsigned short Alds[128 * 64];
  __shared__ unsigned short Blds[128 * 64];
  const int nwg = 1024;  // 128 * 8
  const int wg = blockIdx.x;
  const int swz = (wg & 7) * (nwg >> 3) + (wg >> 3);
  const int mtile = swz >> 3, ntile = swz & 7;
  const int m0 = mtile * 128, n0 = ntile * 128;

  f32x4 acc[4][4] = {};
  gemm_tile_compute(Cs, WoT, DIM, m0, n0, Alds, Blds, acc, threadIdx.x);

  const int lane = threadIdx.x & 63, w = threadIdx.x >> 6;
  const int mg0 = m0 + (w >> 1) * 64, ng0 = n0 + (w & 1) * 64;
#pragma unroll
  for (int mt = 0; mt < 4; ++mt)
#pragma unroll
    for (int nt = 0; nt < 4; ++nt) {
      int ng = ng0 + nt * 16 + (lane & 15);
      int mg = mg0 + mt * 16 + ((lane >> 4) << 2);
#pragma unroll
      for (int r = 0; r < 4; ++r) {
        int m = mg + r;
        int s = m & (SEQ - 1);
        // count = 1 at edges (s<128 or s>=3968), else 2; 1e-8 vanishes in fp32
        float scl = (s < 128 || s >= SEQ - 128) ? 1.0f : 0.5f;
        out[(size_t)m * DIM + ng] = acc[mt][nt][r] * scl;
      }
    }
}

// ---------------- attention: one block per (b, window, head) ----------------
// 4 waves; wave w owns q-rows [w*64, w*64+64). Flash-style online softmax over
// 4 key-chunks of 64. Stats/P layout follow verified C/D mapping:
// row = 4*(lane>>4)+reg, col = lane&15.

__global__ __launch_bounds__(256) void attn_k(const unsigned short* __restrict__ Qb,
                                              const unsigned short* __restrict__ Kb,
                                              const unsigned short* __restrict__ Vt,
                                              unsigned short* __restrict__ ctxA,
                                              unsigned short* __restrict__ ctxB) {
  __shared__ unsigned short Q_lds[256 * 64];   // 32 KB [row][64k] swizzled
  __shared__ unsigned short K_lds[256 * 64];   // 32 KB
  __shared__ unsigned short V_lds[64 * 256];   // 32 KB [d][256 keys] swizzled
  __shared__ unsigned short P_lds[4][64 * 64]; // 8 KB per wave

  const int bid = blockIdx.x;
  const int h = bid & 15;
  const int rem = bid >> 4;
  const int n = rem % NWIN;
  const int b = rem / NWIN;
  const int tid = threadIdx.x;
  const int lane = tid & 63;
  const int w = tid >> 6;

  char* Qc = (char*)Q_lds;
  char* Kc = (char*)K_lds;
  char* Vc = (char*)V_lds;

  // ---- stage Q,K (rowbytes 128, 8 rows per wave-op) ----
  {
    const int srow = lane >> 3, schunk = lane & 7;
    const int sxor8 = (schunk ^ srow) * 8;
    const size_t qkbase = ((size_t)b * SEQ + (size_t)n * 128) * DIM + h * 64;
    const unsigned short* Qg = Qb + qkbase + (size_t)(w * 64 + srow) * DIM + sxor8;
    const unsigned short* Kg = Kb + qkbase + (size_t)(w * 64 + srow) * DIM + sxor8;
#pragma unroll
    for (int j = 0; j < 8; ++j) {
      gll16(Qg + (size_t)j * 8 * DIM, Qc + (w * 64 + j * 8) * 128);
      gll16(Kg + (size_t)j * 8 * DIM, Kc + (w * 64 + j * 8) * 128);
    }
  }
  // ---- stage V^T (rowbytes 512, 2 rows per wave-op) ----
  {
    const int c = lane & 31, rh = lane >> 5;
#pragma unroll
    for (int j = 0; j < 8; ++j) {
      int r = w * 16 + j * 2 + rh;
      int sx = (c ^ (r & 7)) * 8;
      gll16(Vt + (size_t)(h * 64 + r) * (4 * SEQ) + (size_t)b * SEQ + n * 128 + sx,
            Vc + (w * 16 + j * 2) * 512);
    }
  }
  __syncthreads();

  // ---- hoist Q fragments ----
  bf16x8 aq[4][2];
#pragma unroll
  for (int qt = 0; qt < 4; ++qt) {
    int row = w * 64 + qt * 16 + (lane & 15);
#pragma unroll
    for (int kf = 0; kf < 2; ++kf)
      aq[qt][kf] = *(const bf16x8*)(Qc + row * 128 + (((kf * 4 + (lane >> 4)) ^ (lane & 7)) << 4));
  }

  f32x4 acc[4][4] = {};
  float runm[4][4], runs[4][4];
#pragma unroll
  for (int i = 0; i < 4; ++i)
#pragma unroll
    for (int j = 0; j < 4; ++j) { runm[i][j] = -1e30f; runs[i][j] = 0.f; }
  const float csc = 0.18033688011112042f;  // log2(e)/sqrt(dh)
  char* Pc = (char*)(P_lds[w]);

  for (int kc = 0; kc < 4; ++kc) {
#pragma unroll
    for (int qt = 0; qt < 4; ++qt) {
      f32x4 sc4[4] = {};
#pragma unroll
      for (int kt = 0; kt < 4; ++kt) {
        int row = kc * 64 + kt * 16 + (lane & 15);
#pragma unroll
        for (int kf = 0; kf < 2; ++kf) {
          bf16x8 bk = *(const bf16x8*)(Kc + row * 128 + (((kf * 4 + (lane >> 4)) ^ (lane & 7)) << 4));
          sc4[kt] = MFMA(aq[qt][kf], bk, sc4[kt]);
        }
      }
      // online softmax per q-row (rows live in 16-lane groups; butterfly over lane&15)
#pragma unroll
      for (int r = 0; r < 4; ++r) {
        float cm = fmaxf(fmaxf(sc4[0][r], sc4[1][r]), fmaxf(sc4[2][r], sc4[3][r]));
        cm = fmaxf(cm, __shfl_xor(cm, 1));
        cm = fmaxf(cm, __shfl_xor(cm, 2));
        cm = fmaxf(cm, __shfl_xor(cm, 4));
        cm = fmaxf(cm, __shfl_xor(cm, 8));
        float nm = fmaxf(runm[qt][r], cm);
        float fsc = exp2f((runm[qt][r] - nm) * csc);
        runm[qt][r] = nm;
        runs[qt][r] *= fsc;
        acc[qt][0][r] *= fsc; acc[qt][1][r] *= fsc;
        acc[qt][2][r] *= fsc; acc[qt][3][r] *= fsc;
        float ps = 0.f;
        int prow = qt * 16 + ((lane >> 4) << 2) + r;
        int pr7 = prow & 7;
#pragma unroll
        for (int kt = 0; kt < 4; ++kt) {
          float p = exp2f((sc4[kt][r] - nm) * csc);
          ps += p;
          int col = kt * 16 + (lane & 15);
          *(unsigned short*)(Pc + prow * 128 + (((col >> 3) ^ pr7) << 4) + ((col & 7) << 1)) = f2bf(p);
        }
        ps += __shfl_xor(ps, 1);
        ps += __shfl_xor(ps, 2);
        ps += __shfl_xor(ps, 4);
        ps += __shfl_xor(ps, 8);
        runs[qt][r] += ps;
      }
    }
    // ---- PV for this key-chunk (P_lds is wave-private; compiler orders via lgkmcnt) ----
#pragma unroll
    for (int kf = 0; kf < 2; ++kf) {
      bf16x8 bv[4];
#pragma unroll
      for (int dt = 0; dt < 4; ++dt) {
        int row = dt * 16 + (lane & 15);
        int chunk = kc * 8 + kf * 4 + (lane >> 4);
        bv[dt] = *(const bf16x8*)(Vc + row * 512 + ((chunk ^ (lane & 7)) << 4));
      }
#pragma unroll
      for (int qt = 0; qt < 4; ++qt) {
        int prow = qt * 16 + (lane & 15);
        bf16x8 ap = *(const bf16x8*)(Pc + prow * 128 + (((kf * 4 + (lane >> 4)) ^ (lane & 7)) << 4));
#pragma unroll
        for (int dt = 0; dt < 4; ++dt)
          acc[qt][dt] = MFMA(ap, bv[dt], acc[qt][dt]);
      }
    }
  }

  // ---- epilogue: ctx = acc / rowsum, scatter to parity buffer ----
  unsigned short* outb = (n & 1) ? ctxB : ctxA;
  const size_t obase = ((size_t)b * SEQ + (size_t)n * 128 + w * 64) * DIM + h * 64;
#pragma unroll
  for (int qt = 0; qt < 4; ++qt)
#pragma unroll
    for (int r = 0; r < 4; ++r) {
      float inv = 1.0f / runs[qt][r];
      int mrow = qt * 16 + ((lane >> 4) << 2) + r;
#pragma unroll
      for (int dt = 0; dt < 4; ++dt)
        outb[obase + (size_t)mrow * DIM + dt * 16 + (lane & 15)] = f2bf(acc[qt][dt][r] * inv);
    }
}

// ---------------- launch ----------------

extern "C" void kernel_launch(void* const* d_in, const int* in_sizes, int n_in,
                              void* d_out, int out_size, void* d_ws, size_t ws_size,
                              hipStream_t stream) {
  const float* X  = (const float*)d_in[0];
  const float* Wq = (const float*)d_in[1];
  const float* Wk = (const float*)d_in[2];
  const float* Wv = (const float*)d_in[3];
  const float* Wo = (const float*)d_in[4];
  float* out = (float*)d_out;

  char* ws = (char*)d_ws;
  const size_t SZ = (size_t)4 * SEQ * DIM * 2;  // 33,554,432 B (one bf16 [16384][1024])
  unsigned short* Xb   = (unsigned short*)(ws);              // also reused as ctxS
  unsigned short* Wt3  = (unsigned short*)(ws + SZ);         // [3072][1024]
  unsigned short* WoT  = (unsigned short*)(ws + SZ + 6291456);
  unsigned short* Qb   = (unsigned short*)(ws + SZ + 8388608);
  unsigned short* Kb   = (unsigned short*)(ws + 2 * SZ + 8388608);
  unsigned short* Vt   = (unsigned short*)(ws + 3 * SZ + 8388608);
  unsigned short* ctxA = (unsigned short*)(ws + 4 * SZ + 8388608);
  unsigned short* ctxB = (unsigned short*)(ws + 5 * SZ + 8388608);
  // total: 6*SZ + 8 MB = 209,715,200 B

  // odd-window buffer rows [0,128) and [3968,4096) are never written -> zero it
  hipMemsetAsync(ctxB, 0, SZ, stream);

  cast_x_k<<<8192, 256, 0, stream>>>(X, Xb);
  tcast_w_k<<<1024, 256, 0, stream>>>(Wq, Wk, Wv, Wo, Wt3, WoT);
  gemm_qkv_k<<<3072, 256, 0, stream>>>(Xb, Wt3, Qb, Kb, Vt);
  attn_k<<<4 * NWIN * NHEAD, 256, 0, stream>>>(Qb, Kb, Vt, ctxA, ctxB);
  sum_ctx_k<<<8192, 256, 0, stream>>>(ctxA, ctxB, Xb /* ctxS alias */);
  gemm_out_k<<<1024, 256, 0, stream>>>(Xb, WoT, out);
}

// Round 2
// 322.880 us; speedup vs baseline: 1.5168x; 1.5168x over previous
//
#include <hip/hip_runtime.h>

// Problem constants (B=4, S=4096, D=1024, H=16, dh=64, WIN=256, STRIDE=128, nw=31)
#define SEQ 4096
#define DIM 1024
#define NWIN 31
#define NHEAD 16

typedef __attribute__((ext_vector_type(8))) short bf16x8;
typedef __attribute__((ext_vector_type(4))) float f32x4;

#define MFMA(a, b, c) __builtin_amdgcn_mfma_f32_16x16x32_bf16((a), (b), (c), 0, 0, 0)

__device__ __forceinline__ unsigned short f2bf(float f) {
  union { float f; unsigned u; } v; v.f = f;
  unsigned r = v.u + 0x7FFFu + ((v.u >> 16) & 1u);
  return (unsigned short)(r >> 16);
}
__device__ __forceinline__ float bf2f(unsigned short h) {
  union { unsigned u; float f; } v; v.u = ((unsigned)h) << 16;
  return v.f;
}
__device__ __forceinline__ unsigned pk2bf(float a, float b) {
  return (unsigned)f2bf(a) | ((unsigned)f2bf(b) << 16);
}

// async global->LDS, 16B per lane. LDS dest = wave-uniform base + lane*16.
__device__ __forceinline__ void gll16(const void* g, void* l) {
  __builtin_amdgcn_global_load_lds((const __attribute__((address_space(1))) unsigned*)g,
                                   (__attribute__((address_space(3))) unsigned*)l,
                                   16, 0, 0);
}

// ---------------- elementwise cast / sum ----------------

__global__ __launch_bounds__(256) void cast_x_k(const float* __restrict__ x,
                                                unsigned short* __restrict__ o) {
  size_t i = ((size_t)blockIdx.x * 256 + threadIdx.x) * 8;
  float4 a = *(const float4*)(x + i);
  float4 b = *(const float4*)(x + i + 4);
  union { unsigned short u[8]; uint4 v; } pk;
  pk.u[0] = f2bf(a.x); pk.u[1] = f2bf(a.y); pk.u[2] = f2bf(a.z); pk.u[3] = f2bf(a.w);
  pk.u[4] = f2bf(b.x); pk.u[5] = f2bf(b.y); pk.u[6] = f2bf(b.z); pk.u[7] = f2bf(b.w);
  *(uint4*)(o + i) = pk.v;
}

__global__ __launch_bounds__(256) void sum_ctx_k(const unsigned short* __restrict__ a,
                                                 const unsigned short* __restrict__ b,
                                                 unsigned short* __restrict__ o) {
  size_t i = ((size_t)blockIdx.x * 256 + threadIdx.x) * 8;
  union { unsigned short u[8]; uint4 v; } pa, pb, po;
  pa.v = *(const uint4*)(a + i);
  pb.v = *(const uint4*)(b + i);
#pragma unroll
  for (int j = 0; j < 8; ++j) po.u[j] = f2bf(bf2f(pa.u[j]) + bf2f(pb.u[j]));
  *(uint4*)(o + i) = po.v;
}

// ---------------- weight transpose + cast: Wt[n][k] = bf16(W[k][n]) ----------------

__global__ __launch_bounds__(256) void tcast_w_k(const float* __restrict__ W0, const float* __restrict__ W1,
                                                 const float* __restrict__ W2, const float* __restrict__ W3,
                                                 unsigned short* __restrict__ Wt3,
                                                 unsigned short* __restrict__ WoT) {
  __shared__ float tile[64][65];
  const int bid = blockIdx.x;
  const int mat = bid >> 8;
  const int t = bid & 255;
  const int tr = (t >> 4) * 64, tc = (t & 15) * 64;
  const float* W = (mat == 0) ? W0 : (mat == 1) ? W1 : (mat == 2) ? W2 : W3;
  unsigned short* out = (mat < 3) ? (Wt3 + (size_t)mat * 1024 * 1024) : WoT;
  const int tid = threadIdx.x;
  const int rr = tid >> 4, cc = (tid & 15) << 2;
#pragma unroll
  for (int i = 0; i < 4; ++i) {
    int r = i * 16 + rr;
    float4 v = *(const float4*)(W + (size_t)(tr + r) * DIM + tc + cc);
    tile[r][cc] = v.x; tile[r][cc + 1] = v.y; tile[r][cc + 2] = v.z; tile[r][cc + 3] = v.w;
  }
  __syncthreads();
#pragma unroll
  for (int i = 0; i < 4; ++i) {
    int orow = i * 16 + rr;
    union { unsigned short u[4]; uint2 v; } pk;
#pragma unroll
    for (int j = 0; j < 4; ++j) pk.u[j] = f2bf(tile[cc + j][orow]);
    *(uint2*)(out + (size_t)(tc + orow) * DIM + tr + cc) = pk.v;
  }
}

// ---------------- shared GEMM core: C[128x128] = A[128xK] * Bt[128xK]^T ----------------
// A row-major [M][K], Bt row-major [N][K], bf16. LDS tiles XOR-swizzled
// (chunk ^= row&7 in 16B units) so ds_read_b128 fragment loads are ~2-way.

__device__ __forceinline__ void gemm_tile_compute(const unsigned short* __restrict__ A,
                                                  const unsigned short* __restrict__ Bt,
                                                  int K, int m0, int n0,
                                                  unsigned short* Alds, unsigned short* Blds,
                                                  f32x4 acc[4][4], int tid) {
  const int lane = tid & 63;
  const int w = tid >> 6;
  const int srow = lane >> 3, schunk = lane & 7;
  const int sxor = (schunk ^ srow) * 8;  // element offset of the pre-swizzled 16B chunk
  char* Ac = (char*)Alds;
  char* Bc = (char*)Blds;
  const int wr = (w >> 1) * 64, wc = (w & 1) * 64;

  int aoff[4][2], boff[4][2];
#pragma unroll
  for (int t = 0; t < 4; ++t) {
    int ra = wr + t * 16 + (lane & 15);
    int rb = wc + t * 16 + (lane & 15);
#pragma unroll
    for (int kf = 0; kf < 2; ++kf) {
      aoff[t][kf] = ra * 128 + (((kf * 4 + (lane >> 4)) ^ (ra & 7)) << 4);
      boff[t][kf] = rb * 128 + (((kf * 4 + (lane >> 4)) ^ (rb & 7)) << 4);
    }
  }

  const int nk = K >> 6;
  for (int kb = 0; kb < nk; ++kb) {
    const unsigned short* Ag = A + (size_t)(m0 + w * 32 + srow) * K + kb * 64 + sxor;
    const unsigned short* Bg = Bt + (size_t)(n0 + w * 32 + srow) * K + kb * 64 + sxor;
#pragma unroll
    for (int j = 0; j < 4; ++j) {
      gll16(Ag + (size_t)j * 8 * K, Ac + (w * 32 + j * 8) * 128);
      gll16(Bg + (size_t)j * 8 * K, Bc + (w * 32 + j * 8) * 128);
    }
    __syncthreads();  // drains vmcnt: staged data visible
#pragma unroll
    for (int kf = 0; kf < 2; ++kf) {
      bf16x8 af[4], bfr[4];
#pragma unroll
      for (int t = 0; t < 4; ++t) af[t] = *(const bf16x8*)(Ac + aoff[t][kf]);
#pragma unroll
      for (int t = 0; t < 4; ++t) bfr[t] = *(const bf16x8*)(Bc + boff[t][kf]);
#pragma unroll
      for (int mt = 0; mt < 4; ++mt)
#pragma unroll
        for (int nt = 0; nt < 4; ++nt)
          acc[mt][nt] = MFMA(af[mt], bfr[nt], acc[mt][nt]);
    }
    __syncthreads();  // all reads done before next-stage overwrite
  }
}

// ---------------- GEMM 1: [Q|K|V] = Xb @ W, V written transposed ----------------

__global__ __launch_bounds__(256) void gemm_qkv_k(const unsigned short* __restrict__ Xb,
                                                  const unsigned short* __restrict__ Wt3,
                                                  unsigned short* __restrict__ Qb,
                                                  unsigned short* __restrict__ Kb,
                                                  unsigned short* __restrict__ Vt) {
  __shared__ unsigned short Alds[128 * 64];
  __shared__ unsigned short Blds[128 * 64];
  const int nwg = 3072;  // 128 m-tiles * 24 n-tiles
  const int wg = blockIdx.x;
  const int swz = (wg & 7) * (nwg >> 3) + (wg >> 3);  // XCD-aware (nwg % 8 == 0)
  const int mtile = swz / 24, ntile = swz % 24;       // n fast: A-panel L2 reuse
  const int m0 = mtile * 128, n0 = ntile * 128;

  f32x4 acc[4][4] = {};
  gemm_tile_compute(Xb, Wt3, DIM, m0, n0, Alds, Blds, acc, threadIdx.x);

  const int lane = threadIdx.x & 63, w = threadIdx.x >> 6;
  const int mg0 = m0 + (w >> 1) * 64, ng0 = n0 + (w & 1) * 64;
  if (n0 < 2048) {
    unsigned short* O = (n0 < 1024) ? Qb : Kb;
    const int nb = (n0 < 1024) ? 0 : 1024;
#pragma unroll
    for (int mt = 0; mt < 4; ++mt)
#pragma unroll
      for (int nt = 0; nt < 4; ++nt) {
        int ng = ng0 + nt * 16 + (lane & 15) - nb;
        int mg = mg0 + mt * 16 + ((lane >> 4) << 2);
#pragma unroll
        for (int r = 0; r < 4; ++r)
          O[(size_t)(mg + r) * DIM + ng] = f2bf(acc[mt][nt][r]);
      }
  } else {
    // V: store transposed Vt[d_global][m], so attention B-operand reads are contiguous in k
#pragma unroll
    for (int mt = 0; mt < 4; ++mt)
#pragma unroll
      for (int nt = 0; nt < 4; ++nt) {
        int ng = ng0 + nt * 16 + (lane & 15) - 2048;
        int mg = mg0 + mt * 16 + ((lane >> 4) << 2);
        union { unsigned short u[4]; uint2 v; } pk;
#pragma unroll
        for (int r = 0; r < 4; ++r) pk.u[r] = f2bf(acc[mt][nt][r]);
        *(uint2*)(Vt + (size_t)ng * (4 * SEQ) + mg) = pk.v;
      }
  }
}

// ---------------- GEMM 2: out = (ctxS @ Wo) * rowscale ----------------

__global__ __launch_bounds__(256) void gemm_out_k(const unsigned short* __restrict__ Cs,
                                                  const unsigned short* __restrict__ WoT,
                                                  float* __restrict__ out) {
  __shared__ unsigned short Alds[128 * 64];
  __shared__ unsigned short Blds[128 * 64];
  const int nwg = 1024;  // 128 * 8
  const int wg = blockIdx.x;
  const int swz = (wg & 7) * (nwg >> 3) + (wg >> 3);
  const int mtile = swz >> 3, ntile = swz & 7;
  const int m0 = mtile * 128, n0 = ntile * 128;

  f32x4 acc[4][4] = {};
  gemm_tile_compute(Cs, WoT, DIM, m0, n0, Alds, Blds, acc, threadIdx.x);

  const int lane = threadIdx.x & 63, w = threadIdx.x >> 6;
  const int mg0 = m0 + (w >> 1) * 64, ng0 = n0 + (w & 1) * 64;
#pragma unroll
  for (int mt = 0; mt < 4; ++mt)
#pragma unroll
    for (int nt = 0; nt < 4; ++nt) {
      int ng = ng0 + nt * 16 + (lane & 15);
      int mg = mg0 + mt * 16 + ((lane >> 4) << 2);
#pragma unroll
      for (int r = 0; r < 4; ++r) {
        int m = mg + r;
        int s = m & (SEQ - 1);
        // count = 1 at edges (s<128 or s>=3968), else 2; 1e-8 vanishes in fp32
        float scl = (s < 128 || s >= SEQ - 128) ? 1.0f : 0.5f;
        out[(size_t)m * DIM + ng] = acc[mt][nt][r] * scl;
      }
    }
}

// ---------------- attention v2: swapped-operand flash, no P/Q LDS ----------------
// One block per (b, window, head), 4 waves, wave w owns q-rows [w*64, w*64+64).
// QK^T swapped: S^T = mfma(A=K, B=Q)  -> lane holds q = lane&15, k = 16*kt + g*4 + r.
// PV swapped:  ctx^T = mfma(A=V^T, B=P^T) with permuted contraction order
//   pos (g*8+j) -> k = c*32 + (j>>2)*16 + g*4 + (j&3)
// so the P fragment is the lane's OWN 16 probabilities (no cross-lane moves),
// and the V^T fragment is two 8B reads per 32-k chunk. Softmax stats and the
// ctx^T accumulator both have q on lane&15 -> rescale is a scalar multiply.
// LDS = K(32KB) + V^T(32KB) = 64KB -> 2 blocks/CU; VGPR<=256 -> 8 waves/CU.

__global__ __launch_bounds__(256, 2) void attn_k(const unsigned short* __restrict__ Qb,
                                                 const unsigned short* __restrict__ Kb,
                                                 const unsigned short* __restrict__ Vt,
                                                 unsigned short* __restrict__ ctxA,
                                                 unsigned short* __restrict__ ctxB) {
  __shared__ unsigned short K_lds[256 * 64];   // 32 KB [256 k-rows][64 d] swizzled
  __shared__ unsigned short V_lds[64 * 256];   // 32 KB [64 d-rows][256 k] swizzled

  const int bid = blockIdx.x;
  const int h = bid & 15;
  const int rem = bid >> 4;
  const int n = rem % NWIN;
  const int b = rem / NWIN;
  const int tid = threadIdx.x;
  const int lane = tid & 63;
  const int w = tid >> 6;
  const int l15 = lane & 15;
  const int g = lane >> 4;

  char* Kc = (char*)K_lds;
  char* Vc = (char*)V_lds;

  const size_t qkbase = ((size_t)b * SEQ + (size_t)n * 128) * DIM + h * 64;

  // ---- stage K (rowbytes 128, 8 rows per wave-op, 16B chunk ^= row&7) ----
  {
    const int srow = lane >> 3, schunk = lane & 7;
    const int sxor8 = (schunk ^ srow) * 8;
    const unsigned short* Kg = Kb + qkbase + (size_t)(w * 64 + srow) * DIM + sxor8;
#pragma unroll
    for (int j = 0; j < 8; ++j)
      gll16(Kg + (size_t)j * 8 * DIM, Kc + (w * 64 + j * 8) * 128);
  }
  // ---- stage V^T (rowbytes 512, 2 rows per wave-op) ----
  {
    const int c = lane & 31, rh = lane >> 5;
#pragma unroll
    for (int j = 0; j < 8; ++j) {
      int r = w * 16 + j * 2 + rh;
      int sx = (c ^ (r & 7)) * 8;
      gll16(Vt + (size_t)(h * 64 + r) * (4 * SEQ) + (size_t)b * SEQ + n * 128 + sx,
            Vc + (w * 16 + j * 2) * 512);
    }
  }

  // ---- Q fragments direct from global (B-operand: q = l15, d = kf*32 + g*8 + j) ----
  bf16x8 qf[4][2];
#pragma unroll
  for (int qt = 0; qt < 4; ++qt)
#pragma unroll
    for (int kf = 0; kf < 2; ++kf)
      qf[qt][kf] = *(const bf16x8*)(Qb + qkbase +
                                    (size_t)(w * 64 + qt * 16 + l15) * DIM + kf * 32 + g * 8);

  __syncthreads();

  f32x4 acc[4][4] = {};   // acc[qt][dt]: ctx^T, q = qt*16+l15, d = dt*16+g*4+r
  float runm[4], runs[4];
#pragma unroll
  for (int i = 0; i < 4; ++i) { runm[i] = -1e30f; runs[i] = 0.f; }
  const float csc = 0.18033688011112042f;  // log2(e)/sqrt(dh)

  for (int kc = 0; kc < 4; ++kc) {
    // K fragments (A-operand: k-row = kc*64 + kt*16 + l15, d = kf*32 + g*8 + j)
    bf16x8 kfr[4][2];
#pragma unroll
    for (int kt = 0; kt < 4; ++kt) {
      int row = kc * 64 + kt * 16 + l15;
#pragma unroll
      for (int kf = 0; kf < 2; ++kf)
        kfr[kt][kf] = *(const bf16x8*)(Kc + row * 128 + (((kf * 4 + g) ^ (row & 7)) << 4));
    }
    // V^T fragments (A-operand with permuted k order): per (c,dt) two 8B reads
    bf16x8 vf[2][4];
#pragma unroll
    for (int c = 0; c < 2; ++c)
#pragma unroll
      for (int dt = 0; dt < 4; ++dt) {
        int row = dt * 16 + l15;
        int c16 = kc * 8 + c * 4 + (g >> 1);
        int off = (g & 1) * 8;
        union { uint2 u2[2]; bf16x8 v; } vv;
        vv.u2[0] = *(const uint2*)(Vc + row * 512 + ((c16 ^ (row & 7)) << 4) + off);
        vv.u2[1] = *(const uint2*)(Vc + row * 512 + (((c16 + 2) ^ (row & 7)) << 4) + off);
        vf[c][dt] = vv.v;
      }

#pragma unroll
    for (int qt = 0; qt < 4; ++qt) {
      // S^T fragments: lane holds q = qt*16+l15, k = kc*64 + kt*16 + g*4 + r
      f32x4 sc[4] = {};
#pragma unroll
      for (int kt = 0; kt < 4; ++kt)
#pragma unroll
        for (int kf = 0; kf < 2; ++kf)
          sc[kt] = MFMA(kfr[kt][kf], qf[qt][kf], sc[kt]);

      // online softmax: row lives in 4 lanes {l, l^16, l^32, l^48}
      float cm = fmaxf(fmaxf(fmaxf(sc[0][0], sc[0][1]), fmaxf(sc[0][2], sc[0][3])),
                       fmaxf(fmaxf(sc[1][0], sc[1][1]), fmaxf(sc[1][2], sc[1][3])));
      cm = fmaxf(cm, fmaxf(fmaxf(fmaxf(sc[2][0], sc[2][1]), fmaxf(sc[2][2], sc[2][3])),
                           fmaxf(fmaxf(sc[3][0], sc[3][1]), fmaxf(sc[3][2], sc[3][3]))));
      cm = fmaxf(cm, __shfl_xor(cm, 16));
      cm = fmaxf(cm, __shfl_xor(cm, 32));
      float nm = fmaxf(runm[qt], cm);
      float fsc = exp2f((runm[qt] - nm) * csc);
      runm[qt] = nm;
      float ps = 0.f;
#pragma unroll
      for (int kt = 0; kt < 4; ++kt)
#pragma unroll
        for (int r = 0; r < 4; ++r) {
          float p = exp2f((sc[kt][r] - nm) * csc);
          sc[kt][r] = p;
          ps += p;
        }
      ps += __shfl_xor(ps, 16);
      ps += __shfl_xor(ps, 32);
      runs[qt] = runs[qt] * fsc + ps;
#pragma unroll
      for (int dt = 0; dt < 4; ++dt) {
        acc[qt][dt][0] *= fsc; acc[qt][dt][1] *= fsc;
        acc[qt][dt][2] *= fsc; acc[qt][dt][3] *= fsc;
      }
      // P fragments (B-operand, permuted k order = lane's own scores) + PV
#pragma unroll
      for (int c = 0; c < 2; ++c) {
        union { unsigned u[4]; bf16x8 v; } pa;
        pa.u[0] = pk2bf(sc[2 * c][0], sc[2 * c][1]);
        pa.u[1] = pk2bf(sc[2 * c][2], sc[2 * c][3]);
        pa.u[2] = pk2bf(sc[2 * c + 1][0], sc[2 * c + 1][1]);
        pa.u[3] = pk2bf(sc[2 * c + 1][2], sc[2 * c + 1][3]);
#pragma unroll
        for (int dt = 0; dt < 4; ++dt)
          acc[qt][dt] = MFMA(vf[c][dt], pa.v, acc[qt][dt]);
      }
    }
  }

  // ---- epilogue: ctx^T -> ctx, packed 8B stores ----
  unsigned short* outb = (n & 1) ? ctxB : ctxA;
  const size_t obase = ((size_t)b * SEQ + (size_t)n * 128 + w * 64) * DIM + h * 64;
#pragma unroll
  for (int qt = 0; qt < 4; ++qt) {
    float inv = 1.0f / runs[qt];  // q = qt*16 + l15: matches acc layout
#pragma unroll
    for (int dt = 0; dt < 4; ++dt) {
      union { unsigned short u[4]; uint2 v; } pk;
#pragma unroll
      for (int r = 0; r < 4; ++r) pk.u[r] = f2bf(acc[qt][dt][r] * inv);
      *(uint2*)(outb + obase + (size_t)(qt * 16 + l15) * DIM + dt * 16 + g * 4) = pk.v;
    }
  }
}

// ---------------- launch ----------------

extern "C" void kernel_launch(void* const* d_in, const int* in_sizes, int n_in,
                              void* d_out, int out_size, void* d_ws, size_t ws_size,
                              hipStream_t stream) {
  const float* X  = (const float*)d_in[0];
  const float* Wq = (const float*)d_in[1];
  const float* Wk = (const float*)d_in[2];
  const float* Wv = (const float*)d_in[3];
  const float* Wo = (const float*)d_in[4];
  float* out = (float*)d_out;

  char* ws = (char*)d_ws;
  const size_t SZ = (size_t)4 * SEQ * DIM * 2;  // 33,554,432 B (one bf16 [16384][1024])
  unsigned short* Xb   = (unsigned short*)(ws);              // also reused as ctxS
  unsigned short* Wt3  = (unsigned short*)(ws + SZ);         // [3072][1024]
  unsigned short* WoT  = (unsigned short*)(ws + SZ + 6291456);
  unsigned short* Qb   = (unsigned short*)(ws + SZ + 8388608);
  unsigned short* Kb   = (unsigned short*)(ws + 2 * SZ + 8388608);
  unsigned short* Vt   = (unsigned short*)(ws + 3 * SZ + 8388608);
  unsigned short* ctxA = (unsigned short*)(ws + 4 * SZ + 8388608);
  unsigned short* ctxB = (unsigned short*)(ws + 5 * SZ + 8388608);
  // total: 6*SZ + 8 MB = 209,715,200 B

  // odd-window buffer rows [0,128) and [3968,4096) are never written -> zero it
  hipMemsetAsync(ctxB, 0, SZ, stream);

  cast_x_k<<<8192, 256, 0, stream>>>(X, Xb);
  tcast_w_k<<<1024, 256, 0, stream>>>(Wq, Wk, Wv, Wo, Wt3, WoT);
  gemm_qkv_k<<<3072, 256, 0, stream>>>(Xb, Wt3, Qb, Kb, Vt);
  attn_k<<<4 * NWIN * NHEAD, 256, 0, stream>>>(Qb, Kb, Vt, ctxA, ctxB);
  sum_ctx_k<<<8192, 256, 0, stream>>>(ctxA, ctxB, Xb /* ctxS alias */);
  gemm_out_k<<<1024, 256, 0, stream>>>(Xb, WoT, out);
}

// Round 3
// 293.552 us; speedup vs baseline: 1.6683x; 1.0999x over previous
//
#include <hip/hip_runtime.h>

// Problem constants (B=4, S=4096, D=1024, H=16, dh=64, WIN=256, STRIDE=128, nw=31)
#define SEQ 4096
#define DIM 1024
#define NWIN 31
#define NHEAD 16
#define NT 16  // K-steps of 64 in DIM=1024

typedef __attribute__((ext_vector_type(8))) short bf16x8;
typedef __attribute__((ext_vector_type(4))) float f32x4;

#define MFMA(a, b, c) __builtin_amdgcn_mfma_f32_16x16x32_bf16((a), (b), (c), 0, 0, 0)

__device__ __forceinline__ unsigned short f2bf(float f) {
  union { float f; unsigned u; } v; v.f = f;
  unsigned r = v.u + 0x7FFFu + ((v.u >> 16) & 1u);
  return (unsigned short)(r >> 16);
}
__device__ __forceinline__ float bf2f(unsigned short h) {
  union { unsigned u; float f; } v; v.u = ((unsigned)h) << 16;
  return v.f;
}
__device__ __forceinline__ unsigned pk2bf(float a, float b) {
  return (unsigned)f2bf(a) | ((unsigned)f2bf(b) << 16);
}

// async global->LDS, 16B per lane. LDS dest = wave-uniform base + lane*16.
__device__ __forceinline__ void gll16(const void* g, void* l) {
  __builtin_amdgcn_global_load_lds((const __attribute__((address_space(1))) unsigned*)g,
                                   (__attribute__((address_space(3))) unsigned*)l,
                                   16, 0, 0);
}

// ---------------- elementwise cast / sum ----------------

__global__ __launch_bounds__(256) void cast_x_k(const float* __restrict__ x,
                                                unsigned short* __restrict__ o) {
  size_t i = ((size_t)blockIdx.x * 256 + threadIdx.x) * 8;
  float4 a = *(const float4*)(x + i);
  float4 b = *(const float4*)(x + i + 4);
  union { unsigned short u[8]; uint4 v; } pk;
  pk.u[0] = f2bf(a.x); pk.u[1] = f2bf(a.y); pk.u[2] = f2bf(a.z); pk.u[3] = f2bf(a.w);
  pk.u[4] = f2bf(b.x); pk.u[5] = f2bf(b.y); pk.u[6] = f2bf(b.z); pk.u[7] = f2bf(b.w);
  *(uint4*)(o + i) = pk.v;
}

__global__ __launch_bounds__(256) void sum_ctx_k(const unsigned short* __restrict__ a,
                                                 const unsigned short* __restrict__ b,
                                                 unsigned short* __restrict__ o) {
  size_t i = ((size_t)blockIdx.x * 256 + threadIdx.x) * 8;
  union { unsigned short u[8]; uint4 v; } pa, pb, po;
  pa.v = *(const uint4*)(a + i);
  pb.v = *(const uint4*)(b + i);
#pragma unroll
  for (int j = 0; j < 8; ++j) po.u[j] = f2bf(bf2f(pa.u[j]) + bf2f(pb.u[j]));
  *(uint4*)(o + i) = po.v;
}

// ---------------- weight transpose + cast: Wt[n][k] = bf16(W[k][n]) ----------------

__global__ __launch_bounds__(256) void tcast_w_k(const float* __restrict__ W0, const float* __restrict__ W1,
                                                 const float* __restrict__ W2, const float* __restrict__ W3,
                                                 unsigned short* __restrict__ Wt3,
                                                 unsigned short* __restrict__ WoT) {
  __shared__ float tile[64][65];
  const int bid = blockIdx.x;
  const int mat = bid >> 8;
  const int t = bid & 255;
  const int tr = (t >> 4) * 64, tc = (t & 15) * 64;
  const float* W = (mat == 0) ? W0 : (mat == 1) ? W1 : (mat == 2) ? W2 : W3;
  unsigned short* out = (mat < 3) ? (Wt3 + (size_t)mat * 1024 * 1024) : WoT;
  const int tid = threadIdx.x;
  const int rr = tid >> 4, cc = (tid & 15) << 2;
#pragma unroll
  for (int i = 0; i < 4; ++i) {
    int r = i * 16 + rr;
    float4 v = *(const float4*)(W + (size_t)(tr + r) * DIM + tc + cc);
    tile[r][cc] = v.x; tile[r][cc + 1] = v.y; tile[r][cc + 2] = v.z; tile[r][cc + 3] = v.w;
  }
  __syncthreads();
#pragma unroll
  for (int i = 0; i < 4; ++i) {
    int orow = i * 16 + rr;
    union { unsigned short u[4]; uint2 v; } pk;
#pragma unroll
    for (int j = 0; j < 4; ++j) pk.u[j] = f2bf(tile[cc + j][orow]);
    *(uint2*)(out + (size_t)(tc + orow) * DIM + tr + cc) = pk.v;
  }
}

// ---------------- 256x256 8-wave pipelined GEMM core ----------------
// A row-major [M][1024], Bt row-major [N][1024], bf16. K-step = 64 (2 kk-halves of 32).
// LDS: A slots [buf][kk][256r][32k] + B slots, 16KB each, 128KB total.
// Staging linear (gll16), fragment reads conflict-free by construction
// (64 lanes cover each 1KB row-block exactly once: addr = l15*64 + g*16).
// 4 phases/K-step: (kk,qn) quadrants, 16 MFMA each; 1 half-tile staged/phase;
// vmcnt(8) at odd phases BEFORE the barrier (4 half-tiles in flight, never 0).

__device__ __forceinline__ void stage_half(const unsigned short* __restrict__ src,
                                           int row0, int kcol0, char* slot, int tid) {
  const int w = tid >> 6;
  const int r0 = tid >> 2;          // rows 0..127 (o=0), +128 (o=1)
  const int c = (tid & 3) * 8;
  gll16(src + (size_t)(row0 + r0) * DIM + kcol0 + c, slot + w * 1024);
  gll16(src + (size_t)(row0 + 128 + r0) * DIM + kcol0 + c, slot + 8192 + w * 1024);
}

__device__ __forceinline__ void gemm256_core(const unsigned short* __restrict__ A,
                                             const unsigned short* __restrict__ Bt,
                                             int m0, int n0, char* lds,
                                             f32x4 acc[8][4], int tid) {
  const int lane = tid & 63, w = tid >> 6;
  const int wm = w >> 2, wn = w & 3;
  const int l15 = lane & 15, g = lane >> 4;

#define ASLOT(b, kk) (lds + ((b) * 2 + (kk)) * 16384)
#define BSLOT(b, kk) (lds + 65536 + ((b) * 2 + (kk)) * 16384)

  const int aoff = (wm * 128 + l15) * 64 + g * 16;  // + mt*1024
  const int boff = (wn * 64 + l15) * 64 + g * 16;   // + nt*1024

  // prologue: K0 all, K1 kk0  (6 half-tiles = 12 loads)
  stage_half(A,  m0, 0,  ASLOT(0, 0), tid);
  stage_half(Bt, n0, 0,  BSLOT(0, 0), tid);
  stage_half(A,  m0, 32, ASLOT(0, 1), tid);
  stage_half(Bt, n0, 32, BSLOT(0, 1), tid);
  stage_half(A,  m0, 64, ASLOT(1, 0), tid);
  stage_half(Bt, n0, 64, BSLOT(1, 0), tid);
  asm volatile("s_waitcnt vmcnt(8)" ::: "memory");
  __builtin_amdgcn_s_barrier();

  for (int s = 0; s < NT; ++s) {
    const int b = s & 1, nb = b ^ 1;
    const int k1 = (s + 1 < NT ? s + 1 : NT - 1) * 64;
    const int k2 = (s + 2 < NT ? s + 2 : NT - 1) * 64;
    char* Ab0 = ASLOT(b, 0); char* Ab1 = ASLOT(b, 1);
    char* Bb0 = BSLOT(b, 0); char* Bb1 = BSLOT(b, 1);
    bf16x8 af[8], bq0, bq1;

    // ===== phase 0 (kk0, qn0): stage A[nb][kk1] <- step s+1 =====
#pragma unroll
    for (int mt = 0; mt < 8; ++mt) af[mt] = *(const bf16x8*)(Ab0 + aoff + mt * 1024);
    bq0 = *(const bf16x8*)(Bb0 + boff);
    bq1 = *(const bf16x8*)(Bb0 + boff + 1024);
    stage_half(A, m0, k1 + 32, ASLOT(nb, 1), tid);
    __builtin_amdgcn_s_barrier();
    asm volatile("s_waitcnt lgkmcnt(0)" ::: "memory");
    __builtin_amdgcn_sched_barrier(0);
    __builtin_amdgcn_s_setprio(1);
#pragma unroll
    for (int mt = 0; mt < 8; ++mt) {
      acc[mt][0] = MFMA(af[mt], bq0, acc[mt][0]);
      acc[mt][1] = MFMA(af[mt], bq1, acc[mt][1]);
    }
    __builtin_amdgcn_s_setprio(0);

    // ===== phase 1 (kk0, qn1): stage B[nb][kk1] <- step s+1, vmcnt =====
    bq0 = *(const bf16x8*)(Bb0 + boff + 2048);
    bq1 = *(const bf16x8*)(Bb0 + boff + 3072);
    stage_half(Bt, n0, k1 + 32, BSLOT(nb, 1), tid);
    asm volatile("s_waitcnt vmcnt(8)" ::: "memory");
    __builtin_amdgcn_s_barrier();
    asm volatile("s_waitcnt lgkmcnt(0)" ::: "memory");
    __builtin_amdgcn_sched_barrier(0);
    __builtin_amdgcn_s_setprio(1);
#pragma unroll
    for (int mt = 0; mt < 8; ++mt) {
      acc[mt][2] = MFMA(af[mt], bq0, acc[mt][2]);
      acc[mt][3] = MFMA(af[mt], bq1, acc[mt][3]);
    }
    __builtin_amdgcn_s_setprio(0);

    // ===== phase 2 (kk1, qn0): stage A[b][kk0] <- step s+2 =====
#pragma unroll
    for (int mt = 0; mt < 8; ++mt) af[mt] = *(const bf16x8*)(Ab1 + aoff + mt * 1024);
    bq0 = *(const bf16x8*)(Bb1 + boff);
    bq1 = *(const bf16x8*)(Bb1 + boff + 1024);
    stage_half(A, m0, k2, ASLOT(b, 0), tid);
    __builtin_amdgcn_s_barrier();
    asm volatile("s_waitcnt lgkmcnt(0)" ::: "memory");
    __builtin_amdgcn_sched_barrier(0);
    __builtin_amdgcn_s_setprio(1);
#pragma unroll
    for (int mt = 0; mt < 8; ++mt) {
      acc[mt][0] = MFMA(af[mt], bq0, acc[mt][0]);
      acc[mt][1] = MFMA(af[mt], bq1, acc[mt][1]);
    }
    __builtin_amdgcn_s_setprio(0);

    // ===== phase 3 (kk1, qn1): stage B[b][kk0] <- step s+2, vmcnt =====
    bq0 = *(const bf16x8*)(Bb1 + boff + 2048);
    bq1 = *(const bf16x8*)(Bb1 + boff + 3072);
    stage_half(Bt, n0, k2, BSLOT(b, 0), tid);
    asm volatile("s_waitcnt vmcnt(8)" ::: "memory");
    __builtin_amdgcn_s_barrier();
    asm volatile("s_waitcnt lgkmcnt(0)" ::: "memory");
    __builtin_amdgcn_sched_barrier(0);
    __builtin_amdgcn_s_setprio(1);
#pragma unroll
    for (int mt = 0; mt < 8; ++mt) {
      acc[mt][2] = MFMA(af[mt], bq0, acc[mt][2]);
      acc[mt][3] = MFMA(af[mt], bq1, acc[mt][3]);
    }
    __builtin_amdgcn_s_setprio(0);
  }
#undef ASLOT
#undef BSLOT
}

// ---------------- GEMM 1: [Q|K|V] = Xb @ W, V written transposed ----------------

__global__ __launch_bounds__(512, 2) void gemm_qkv_k(const unsigned short* __restrict__ Xb,
                                                     const unsigned short* __restrict__ Wt3,
                                                     unsigned short* __restrict__ Qb,
                                                     unsigned short* __restrict__ Kb,
                                                     unsigned short* __restrict__ Vt) {
  __shared__ char lds[131072];
  const int nwg = 768;  // 64 m-tiles * 12 n-tiles
  const int wg = blockIdx.x;
  const int swz = (wg & 7) * (nwg >> 3) + (wg >> 3);  // XCD-aware (768 % 8 == 0)
  const int mtile = swz / 12, ntile = swz % 12;       // n fast: A-panel L2 reuse
  const int m0 = mtile * 256, n0 = ntile * 256;
  const int tid = threadIdx.x;

  f32x4 acc[8][4] = {};
  gemm256_core(Xb, Wt3, m0, n0, lds, acc, tid);

  const int lane = tid & 63, w = tid >> 6;
  const int wm = w >> 2, wn = w & 3;
  const int l15 = lane & 15, g = lane >> 4;
  const int mg0 = m0 + wm * 128;
  const int ng0 = n0 + wn * 64;

  if (n0 < 2048) {
    unsigned short* O = (n0 < 1024) ? Qb : Kb;
    const int nb = (n0 < 1024) ? 0 : 1024;
#pragma unroll
    for (int mt = 0; mt < 8; ++mt)
#pragma unroll
      for (int nt = 0; nt < 4; ++nt) {
        int ng = ng0 + nt * 16 + l15 - nb;
        int mg = mg0 + mt * 16 + g * 4;
#pragma unroll
        for (int r = 0; r < 4; ++r)
          O[(size_t)(mg + r) * DIM + ng] = f2bf(acc[mt][nt][r]);
      }
  } else {
    // V: store transposed Vt[d_global][m]
#pragma unroll
    for (int mt = 0; mt < 8; ++mt)
#pragma unroll
      for (int nt = 0; nt < 4; ++nt) {
        int ng = ng0 + nt * 16 + l15 - 2048;
        int mg = mg0 + mt * 16 + g * 4;
        union { unsigned short u[4]; uint2 v; } pk;
#pragma unroll
        for (int r = 0; r < 4; ++r) pk.u[r] = f2bf(acc[mt][nt][r]);
        *(uint2*)(Vt + (size_t)ng * (4 * SEQ) + mg) = pk.v;
      }
  }
}

// ---------------- GEMM 2: out = (ctxS @ Wo) * rowscale ----------------

__global__ __launch_bounds__(512, 2) void gemm_out_k(const unsigned short* __restrict__ Cs,
                                                     const unsigned short* __restrict__ WoT,
                                                     float* __restrict__ out) {
  __shared__ char lds[131072];
  const int nwg = 256;  // 64 m-tiles * 4 n-tiles
  const int wg = blockIdx.x;
  const int swz = (wg & 7) * (nwg >> 3) + (wg >> 3);
  const int mtile = swz >> 2, ntile = swz & 3;
  const int m0 = mtile * 256, n0 = ntile * 256;
  const int tid = threadIdx.x;

  f32x4 acc[8][4] = {};
  gemm256_core(Cs, WoT, m0, n0, lds, acc, tid);

  const int lane = tid & 63, w = tid >> 6;
  const int wm = w >> 2, wn = w & 3;
  const int l15 = lane & 15, g = lane >> 4;
  const int mg0 = m0 + wm * 128;
  const int ng0 = n0 + wn * 64;
#pragma unroll
  for (int mt = 0; mt < 8; ++mt)
#pragma unroll
    for (int nt = 0; nt < 4; ++nt) {
      int ng = ng0 + nt * 16 + l15;
      int mg = mg0 + mt * 16 + g * 4;
#pragma unroll
      for (int r = 0; r < 4; ++r) {
        int m = mg + r;
        int s = m & (SEQ - 1);
        // count = 1 at edges (s<128 or s>=3968), else 2; 1e-8 vanishes in fp32
        float scl = (s < 128 || s >= SEQ - 128) ? 1.0f : 0.5f;
        out[(size_t)m * DIM + ng] = acc[mt][nt][r] * scl;
      }
    }
}

// ---------------- attention: swapped-operand flash, no P/Q LDS ----------------
// One block per (b, window, head), 4 waves, wave w owns q-rows [w*64, w*64+64).
// QK^T swapped: S^T = mfma(A=K, B=Q)  -> lane holds q = lane&15, k = 16*kt + g*4 + r.
// PV swapped:  ctx^T = mfma(A=V^T, B=P^T) with permuted contraction order
//   pos (g*8+j) -> k = c*32 + (j>>2)*16 + g*4 + (j&3)
// so the P fragment is the lane's OWN 16 probabilities (no cross-lane moves).

__global__ __launch_bounds__(256, 2) void attn_k(const unsigned short* __restrict__ Qb,
                                                 const unsigned short* __restrict__ Kb,
                                                 const unsigned short* __restrict__ Vt,
                                                 unsigned short* __restrict__ ctxA,
                                                 unsigned short* __restrict__ ctxB) {
  __shared__ unsigned short K_lds[256 * 64];   // 32 KB [256 k-rows][64 d] swizzled
  __shared__ unsigned short V_lds[64 * 256];   // 32 KB [64 d-rows][256 k] swizzled

  const int bid = blockIdx.x;
  const int h = bid & 15;
  const int rem = bid >> 4;
  const int n = rem % NWIN;
  const int b = rem / NWIN;
  const int tid = threadIdx.x;
  const int lane = tid & 63;
  const int w = tid >> 6;
  const int l15 = lane & 15;
  const int g = lane >> 4;

  char* Kc = (char*)K_lds;
  char* Vc = (char*)V_lds;

  const size_t qkbase = ((size_t)b * SEQ + (size_t)n * 128) * DIM + h * 64;

  // ---- stage K (rowbytes 128, 8 rows per wave-op, 16B chunk ^= row&7) ----
  {
    const int srow = lane >> 3, schunk = lane & 7;
    const int sxor8 = (schunk ^ srow) * 8;
    const unsigned short* Kg = Kb + qkbase + (size_t)(w * 64 + srow) * DIM + sxor8;
#pragma unroll
    for (int j = 0; j < 8; ++j)
      gll16(Kg + (size_t)j * 8 * DIM, Kc + (w * 64 + j * 8) * 128);
  }
  // ---- stage V^T (rowbytes 512, 2 rows per wave-op) ----
  {
    const int c = lane & 31, rh = lane >> 5;
#pragma unroll
    for (int j = 0; j < 8; ++j) {
      int r = w * 16 + j * 2 + rh;
      int sx = (c ^ (r & 7)) * 8;
      gll16(Vt + (size_t)(h * 64 + r) * (4 * SEQ) + (size_t)b * SEQ + n * 128 + sx,
            Vc + (w * 16 + j * 2) * 512);
    }
  }

  // ---- Q fragments direct from global (B-operand: q = l15, d = kf*32 + g*8 + j) ----
  bf16x8 qf[4][2];
#pragma unroll
  for (int qt = 0; qt < 4; ++qt)
#pragma unroll
    for (int kf = 0; kf < 2; ++kf)
      qf[qt][kf] = *(const bf16x8*)(Qb + qkbase +
                                    (size_t)(w * 64 + qt * 16 + l15) * DIM + kf * 32 + g * 8);

  __syncthreads();

  f32x4 acc[4][4] = {};   // acc[qt][dt]: ctx^T, q = qt*16+l15, d = dt*16+g*4+r
  float runm[4], runs[4];
#pragma unroll
  for (int i = 0; i < 4; ++i) { runm[i] = -1e30f; runs[i] = 0.f; }
  const float csc = 0.18033688011112042f;  // log2(e)/sqrt(dh)

  for (int kc = 0; kc < 4; ++kc) {
    bf16x8 kfr[4][2];
#pragma unroll
    for (int kt = 0; kt < 4; ++kt) {
      int row = kc * 64 + kt * 16 + l15;
#pragma unroll
      for (int kf = 0; kf < 2; ++kf)
        kfr[kt][kf] = *(const bf16x8*)(Kc + row * 128 + (((kf * 4 + g) ^ (row & 7)) << 4));
    }
    bf16x8 vf[2][4];
#pragma unroll
    for (int c = 0; c < 2; ++c)
#pragma unroll
      for (int dt = 0; dt < 4; ++dt) {
        int row = dt * 16 + l15;
        int c16 = kc * 8 + c * 4 + (g >> 1);
        int off = (g & 1) * 8;
        union { uint2 u2[2]; bf16x8 v; } vv;
        vv.u2[0] = *(const uint2*)(Vc + row * 512 + ((c16 ^ (row & 7)) << 4) + off);
        vv.u2[1] = *(const uint2*)(Vc + row * 512 + (((c16 + 2) ^ (row & 7)) << 4) + off);
        vf[c][dt] = vv.v;
      }

#pragma unroll
    for (int qt = 0; qt < 4; ++qt) {
      f32x4 sc[4] = {};
#pragma unroll
      for (int kt = 0; kt < 4; ++kt)
#pragma unroll
        for (int kf = 0; kf < 2; ++kf)
          sc[kt] = MFMA(kfr[kt][kf], qf[qt][kf], sc[kt]);

      float cm = fmaxf(fmaxf(fmaxf(sc[0][0], sc[0][1]), fmaxf(sc[0][2], sc[0][3])),
                       fmaxf(fmaxf(sc[1][0], sc[1][1]), fmaxf(sc[1][2], sc[1][3])));
      cm = fmaxf(cm, fmaxf(fmaxf(fmaxf(sc[2][0], sc[2][1]), fmaxf(sc[2][2], sc[2][3])),
                           fmaxf(fmaxf(sc[3][0], sc[3][1]), fmaxf(sc[3][2], sc[3][3]))));
      cm = fmaxf(cm, __shfl_xor(cm, 16));
      cm = fmaxf(cm, __shfl_xor(cm, 32));
      float nm = fmaxf(runm[qt], cm);
      float fsc = exp2f((runm[qt] - nm) * csc);
      runm[qt] = nm;
      float ps = 0.f;
#pragma unroll
      for (int kt = 0; kt < 4; ++kt)
#pragma unroll
        for (int r = 0; r < 4; ++r) {
          float p = exp2f((sc[kt][r] - nm) * csc);
          sc[kt][r] = p;
          ps += p;
        }
      ps += __shfl_xor(ps, 16);
      ps += __shfl_xor(ps, 32);
      runs[qt] = runs[qt] * fsc + ps;
#pragma unroll
      for (int dt = 0; dt < 4; ++dt) {
        acc[qt][dt][0] *= fsc; acc[qt][dt][1] *= fsc;
        acc[qt][dt][2] *= fsc; acc[qt][dt][3] *= fsc;
      }
#pragma unroll
      for (int c = 0; c < 2; ++c) {
        union { unsigned u[4]; bf16x8 v; } pa;
        pa.u[0] = pk2bf(sc[2 * c][0], sc[2 * c][1]);
        pa.u[1] = pk2bf(sc[2 * c][2], sc[2 * c][3]);
        pa.u[2] = pk2bf(sc[2 * c + 1][0], sc[2 * c + 1][1]);
        pa.u[3] = pk2bf(sc[2 * c + 1][2], sc[2 * c + 1][3]);
#pragma unroll
        for (int dt = 0; dt < 4; ++dt)
          acc[qt][dt] = MFMA(vf[c][dt], pa.v, acc[qt][dt]);
      }
    }
  }

  unsigned short* outb = (n & 1) ? ctxB : ctxA;
  const size_t obase = ((size_t)b * SEQ + (size_t)n * 128 + w * 64) * DIM + h * 64;
#pragma unroll
  for (int qt = 0; qt < 4; ++qt) {
    float inv = 1.0f / runs[qt];
#pragma unroll
    for (int dt = 0; dt < 4; ++dt) {
      union { unsigned short u[4]; uint2 v; } pk;
#pragma unroll
      for (int r = 0; r < 4; ++r) pk.u[r] = f2bf(acc[qt][dt][r] * inv);
      *(uint2*)(outb + obase + (size_t)(qt * 16 + l15) * DIM + dt * 16 + g * 4) = pk.v;
    }
  }
}

// ---------------- launch ----------------

extern "C" void kernel_launch(void* const* d_in, const int* in_sizes, int n_in,
                              void* d_out, int out_size, void* d_ws, size_t ws_size,
                              hipStream_t stream) {
  const float* X  = (const float*)d_in[0];
  const float* Wq = (const float*)d_in[1];
  const float* Wk = (const float*)d_in[2];
  const float* Wv = (const float*)d_in[3];
  const float* Wo = (const float*)d_in[4];
  float* out = (float*)d_out;

  char* ws = (char*)d_ws;
  const size_t SZ = (size_t)4 * SEQ * DIM * 2;  // 33,554,432 B (one bf16 [16384][1024])
  unsigned short* Xb   = (unsigned short*)(ws);              // also reused as ctxS
  unsigned short* Wt3  = (unsigned short*)(ws + SZ);         // [3072][1024]
  unsigned short* WoT  = (unsigned short*)(ws + SZ + 6291456);
  unsigned short* Qb   = (unsigned short*)(ws + SZ + 8388608);
  unsigned short* Kb   = (unsigned short*)(ws + 2 * SZ + 8388608);
  unsigned short* Vt   = (unsigned short*)(ws + 3 * SZ + 8388608);
  unsigned short* ctxA = (unsigned short*)(ws + 4 * SZ + 8388608);
  unsigned short* ctxB = (unsigned short*)(ws + 5 * SZ + 8388608);
  // total: 6*SZ + 8 MB = 209,715,200 B

  // odd-window buffer rows [0,128) and [3968,4096) are never written -> zero it
  hipMemsetAsync(ctxB, 0, SZ, stream);

  cast_x_k<<<8192, 256, 0, stream>>>(X, Xb);
  tcast_w_k<<<1024, 256, 0, stream>>>(Wq, Wk, Wv, Wo, Wt3, WoT);
  gemm_qkv_k<<<768, 512, 0, stream>>>(Xb, Wt3, Qb, Kb, Vt);
  attn_k<<<4 * NWIN * NHEAD, 256, 0, stream>>>(Qb, Kb, Vt, ctxA, ctxB);
  sum_ctx_k<<<8192, 256, 0, stream>>>(ctxA, ctxB, Xb /* ctxS alias */);
  gemm_out_k<<<256, 512, 0, stream>>>(Xb, WoT, out);
}

// Round 4
// 289.169 us; speedup vs baseline: 1.6936x; 1.0152x over previous
//
#include <hip/hip_runtime.h>

// Problem constants (B=4, S=4096, D=1024, H=16, dh=64, WIN=256, STRIDE=128, nw=31)
#define SEQ 4096
#define DIM 1024
#define NWIN 31
#define NHEAD 16
#define NT 16  // K-steps of 64 in DIM=1024

typedef __attribute__((ext_vector_type(8))) short bf16x8;
typedef __attribute__((ext_vector_type(4))) float f32x4;

#define MFMA(a, b, c) __builtin_amdgcn_mfma_f32_16x16x32_bf16((a), (b), (c), 0, 0, 0)

__device__ __forceinline__ unsigned short f2bf(float f) {
  union { float f; unsigned u; } v; v.f = f;
  unsigned r = v.u + 0x7FFFu + ((v.u >> 16) & 1u);
  return (unsigned short)(r >> 16);
}
__device__ __forceinline__ float bf2f(unsigned short h) {
  union { unsigned u; float f; } v; v.u = ((unsigned)h) << 16;
  return v.f;
}
__device__ __forceinline__ unsigned pk2bf(float a, float b) {
  return (unsigned)f2bf(a) | ((unsigned)f2bf(b) << 16);
}

// async global->LDS, 16B per lane. LDS dest = wave-uniform base + lane*16.
__device__ __forceinline__ void gll16(const void* g, void* l) {
  __builtin_amdgcn_global_load_lds((const __attribute__((address_space(1))) unsigned*)g,
                                   (__attribute__((address_space(3))) unsigned*)l,
                                   16, 0, 0);
}

// ---------------- elementwise cast / sum ----------------

__global__ __launch_bounds__(256) void cast_x_k(const float* __restrict__ x,
                                                unsigned short* __restrict__ o) {
  size_t i = ((size_t)blockIdx.x * 256 + threadIdx.x) * 8;
  float4 a = *(const float4*)(x + i);
  float4 b = *(const float4*)(x + i + 4);
  union { unsigned short u[8]; uint4 v; } pk;
  pk.u[0] = f2bf(a.x); pk.u[1] = f2bf(a.y); pk.u[2] = f2bf(a.z); pk.u[3] = f2bf(a.w);
  pk.u[4] = f2bf(b.x); pk.u[5] = f2bf(b.y); pk.u[6] = f2bf(b.z); pk.u[7] = f2bf(b.w);
  *(uint4*)(o + i) = pk.v;
}

__global__ __launch_bounds__(256) void sum_ctx_k(const unsigned short* __restrict__ a,
                                                 const unsigned short* __restrict__ b,
                                                 unsigned short* __restrict__ o) {
  size_t i = ((size_t)blockIdx.x * 256 + threadIdx.x) * 8;
  union { unsigned short u[8]; uint4 v; } pa, pb, po;
  pa.v = *(const uint4*)(a + i);
  pb.v = *(const uint4*)(b + i);
#pragma unroll
  for (int j = 0; j < 8; ++j) po.u[j] = f2bf(bf2f(pa.u[j]) + bf2f(pb.u[j]));
  *(uint4*)(o + i) = po.v;
}

// ---------------- weight transpose + cast: Wt[n][k] = bf16(W[k][n]) ----------------

__global__ __launch_bounds__(256) void tcast_w_k(const float* __restrict__ W0, const float* __restrict__ W1,
                                                 const float* __restrict__ W2, const float* __restrict__ W3,
                                                 unsigned short* __restrict__ Wt3,
                                                 unsigned short* __restrict__ WoT) {
  __shared__ float tile[64][65];
  const int bid = blockIdx.x;
  const int mat = bid >> 8;
  const int t = bid & 255;
  const int tr = (t >> 4) * 64, tc = (t & 15) * 64;
  const float* W = (mat == 0) ? W0 : (mat == 1) ? W1 : (mat == 2) ? W2 : W3;
  unsigned short* out = (mat < 3) ? (Wt3 + (size_t)mat * 1024 * 1024) : WoT;
  const int tid = threadIdx.x;
  const int rr = tid >> 4, cc = (tid & 15) << 2;
#pragma unroll
  for (int i = 0; i < 4; ++i) {
    int r = i * 16 + rr;
    float4 v = *(const float4*)(W + (size_t)(tr + r) * DIM + tc + cc);
    tile[r][cc] = v.x; tile[r][cc + 1] = v.y; tile[r][cc + 2] = v.z; tile[r][cc + 3] = v.w;
  }
  __syncthreads();
#pragma unroll
  for (int i = 0; i < 4; ++i) {
    int orow = i * 16 + rr;
    union { unsigned short u[4]; uint2 v; } pk;
#pragma unroll
    for (int j = 0; j < 4; ++j) pk.u[j] = f2bf(tile[cc + j][orow]);
    *(uint2*)(out + (size_t)(tc + orow) * DIM + tr + cc) = pk.v;
  }
}

// ---------------- 256x256 8-wave pipelined GEMM core ----------------
// A row-major [M][1024], Bt row-major [N][1024], bf16. K-step = 64 (2 kk-halves of 32).
// LDS: A slots [buf][kk][256r][32k] + B slots, 16KB each, 128KB total.
// Bank-conflict fix (round 4): 16B chunk index XOR-swizzled with (row>>1)&3.
// Staging keeps linear LDS dest (gll16 requirement) and pre-swizzles the GLOBAL
// source column; reads XOR the chunk with (l15>>1)&3 (constant per lane since
// mt*16 / wn*64 row steps are 0 mod 8 rows). Colliding lane-octets now spread
// over 4 chunks -> 2-way (free).
// 4 phases/K-step: (kk,qn) quadrants, 16 MFMA each; 1 half-tile staged/phase;
// vmcnt(8) at odd phases BEFORE the barrier (4 half-tiles in flight, never 0).

__device__ __forceinline__ void stage_half(const unsigned short* __restrict__ src,
                                           int row0, int kcol0, char* slot, int tid) {
  const int w = tid >> 6;
  const int r0 = tid >> 2;          // rows 0..127 (o=0), +128 (o=1)
  const int c = (((tid & 3) ^ ((tid >> 3) & 3))) * 8;  // pre-swizzled source column
  gll16(src + (size_t)(row0 + r0) * DIM + kcol0 + c, slot + w * 1024);
  gll16(src + (size_t)(row0 + 128 + r0) * DIM + kcol0 + c, slot + 8192 + w * 1024);
}

__device__ __forceinline__ void gemm256_core(const unsigned short* __restrict__ A,
                                             const unsigned short* __restrict__ Bt,
                                             int m0, int n0, char* lds,
                                             f32x4 acc[8][4], int tid) {
  const int lane = tid & 63, w = tid >> 6;
  const int wm = w >> 2, wn = w & 3;
  const int l15 = lane & 15, g = lane >> 4;
  const int gs = g ^ ((l15 >> 1) & 3);  // swizzled chunk index

#define ASLOT(b, kk) (lds + ((b) * 2 + (kk)) * 16384)
#define BSLOT(b, kk) (lds + 65536 + ((b) * 2 + (kk)) * 16384)

  const int aoff = (wm * 128 + l15) * 64 + gs * 16;  // + mt*1024
  const int boff = (wn * 64 + l15) * 64 + gs * 16;   // + nt*1024

  // prologue: K0 all, K1 kk0  (6 half-tiles = 12 loads)
  stage_half(A,  m0, 0,  ASLOT(0, 0), tid);
  stage_half(Bt, n0, 0,  BSLOT(0, 0), tid);
  stage_half(A,  m0, 32, ASLOT(0, 1), tid);
  stage_half(Bt, n0, 32, BSLOT(0, 1), tid);
  stage_half(A,  m0, 64, ASLOT(1, 0), tid);
  stage_half(Bt, n0, 64, BSLOT(1, 0), tid);
  asm volatile("s_waitcnt vmcnt(8)" ::: "memory");
  __builtin_amdgcn_s_barrier();

  for (int s = 0; s < NT; ++s) {
    const int b = s & 1, nb = b ^ 1;
    const int k1 = (s + 1 < NT ? s + 1 : NT - 1) * 64;
    const int k2 = (s + 2 < NT ? s + 2 : NT - 1) * 64;
    char* Ab0 = ASLOT(b, 0); char* Ab1 = ASLOT(b, 1);
    char* Bb0 = BSLOT(b, 0); char* Bb1 = BSLOT(b, 1);
    bf16x8 af[8], bq0, bq1;

    // ===== phase 0 (kk0, qn0): stage A[nb][kk1] <- step s+1 =====
#pragma unroll
    for (int mt = 0; mt < 8; ++mt) af[mt] = *(const bf16x8*)(Ab0 + aoff + mt * 1024);
    bq0 = *(const bf16x8*)(Bb0 + boff);
    bq1 = *(const bf16x8*)(Bb0 + boff + 1024);
    stage_half(A, m0, k1 + 32, ASLOT(nb, 1), tid);
    __builtin_amdgcn_s_barrier();
    asm volatile("s_waitcnt lgkmcnt(0)" ::: "memory");
    __builtin_amdgcn_sched_barrier(0);
    __builtin_amdgcn_s_setprio(1);
#pragma unroll
    for (int mt = 0; mt < 8; ++mt) {
      acc[mt][0] = MFMA(af[mt], bq0, acc[mt][0]);
      acc[mt][1] = MFMA(af[mt], bq1, acc[mt][1]);
    }
    __builtin_amdgcn_s_setprio(0);

    // ===== phase 1 (kk0, qn1): stage B[nb][kk1] <- step s+1, vmcnt =====
    bq0 = *(const bf16x8*)(Bb0 + boff + 2048);
    bq1 = *(const bf16x8*)(Bb0 + boff + 3072);
    stage_half(Bt, n0, k1 + 32, BSLOT(nb, 1), tid);
    asm volatile("s_waitcnt vmcnt(8)" ::: "memory");
    __builtin_amdgcn_s_barrier();
    asm volatile("s_waitcnt lgkmcnt(0)" ::: "memory");
    __builtin_amdgcn_sched_barrier(0);
    __builtin_amdgcn_s_setprio(1);
#pragma unroll
    for (int mt = 0; mt < 8; ++mt) {
      acc[mt][2] = MFMA(af[mt], bq0, acc[mt][2]);
      acc[mt][3] = MFMA(af[mt], bq1, acc[mt][3]);
    }
    __builtin_amdgcn_s_setprio(0);

    // ===== phase 2 (kk1, qn0): stage A[b][kk0] <- step s+2 =====
#pragma unroll
    for (int mt = 0; mt < 8; ++mt) af[mt] = *(const bf16x8*)(Ab1 + aoff + mt * 1024);
    bq0 = *(const bf16x8*)(Bb1 + boff);
    bq1 = *(const bf16x8*)(Bb1 + boff + 1024);
    stage_half(A, m0, k2, ASLOT(b, 0), tid);
    __builtin_amdgcn_s_barrier();
    asm volatile("s_waitcnt lgkmcnt(0)" ::: "memory");
    __builtin_amdgcn_sched_barrier(0);
    __builtin_amdgcn_s_setprio(1);
#pragma unroll
    for (int mt = 0; mt < 8; ++mt) {
      acc[mt][0] = MFMA(af[mt], bq0, acc[mt][0]);
      acc[mt][1] = MFMA(af[mt], bq1, acc[mt][1]);
    }
    __builtin_amdgcn_s_setprio(0);

    // ===== phase 3 (kk1, qn1): stage B[b][kk0] <- step s+2, vmcnt =====
    bq0 = *(const bf16x8*)(Bb1 + boff + 2048);
    bq1 = *(const bf16x8*)(Bb1 + boff + 3072);
    stage_half(Bt, n0, k2, BSLOT(b, 0), tid);
    asm volatile("s_waitcnt vmcnt(8)" ::: "memory");
    __builtin_amdgcn_s_barrier();
    asm volatile("s_waitcnt lgkmcnt(0)" ::: "memory");
    __builtin_amdgcn_sched_barrier(0);
    __builtin_amdgcn_s_setprio(1);
#pragma unroll
    for (int mt = 0; mt < 8; ++mt) {
      acc[mt][2] = MFMA(af[mt], bq0, acc[mt][2]);
      acc[mt][3] = MFMA(af[mt], bq1, acc[mt][3]);
    }
    __builtin_amdgcn_s_setprio(0);
  }
#undef ASLOT
#undef BSLOT
}

// ---------------- GEMM 1: [Q|K|V] = Xb @ W, V written transposed ----------------

__global__ __launch_bounds__(512, 2) void gemm_qkv_k(const unsigned short* __restrict__ Xb,
                                                     const unsigned short* __restrict__ Wt3,
                                                     unsigned short* __restrict__ Qb,
                                                     unsigned short* __restrict__ Kb,
                                                     unsigned short* __restrict__ Vt) {
  __shared__ char lds[131072];
  const int nwg = 768;  // 64 m-tiles * 12 n-tiles
  const int wg = blockIdx.x;
  const int swz = (wg & 7) * (nwg >> 3) + (wg >> 3);  // XCD-aware (768 % 8 == 0)
  const int mtile = swz / 12, ntile = swz % 12;       // n fast: A-panel L2 reuse
  const int m0 = mtile * 256, n0 = ntile * 256;
  const int tid = threadIdx.x;

  f32x4 acc[8][4] = {};
  gemm256_core(Xb, Wt3, m0, n0, lds, acc, tid);

  const int lane = tid & 63, w = tid >> 6;
  const int wm = w >> 2, wn = w & 3;
  const int l15 = lane & 15, g = lane >> 4;
  const int mg0 = m0 + wm * 128;
  const int ng0 = n0 + wn * 64;

  if (n0 < 2048) {
    unsigned short* O = (n0 < 1024) ? Qb : Kb;
    const int nb = (n0 < 1024) ? 0 : 1024;
#pragma unroll
    for (int mt = 0; mt < 8; ++mt)
#pragma unroll
      for (int nt = 0; nt < 4; ++nt) {
        int ng = ng0 + nt * 16 + l15 - nb;
        int mg = mg0 + mt * 16 + g * 4;
#pragma unroll
        for (int r = 0; r < 4; ++r)
          O[(size_t)(mg + r) * DIM + ng] = f2bf(acc[mt][nt][r]);
      }
  } else {
    // V: store transposed Vt[d_global][m]
#pragma unroll
    for (int mt = 0; mt < 8; ++mt)
#pragma unroll
      for (int nt = 0; nt < 4; ++nt) {
        int ng = ng0 + nt * 16 + l15 - 2048;
        int mg = mg0 + mt * 16 + g * 4;
        union { unsigned short u[4]; uint2 v; } pk;
#pragma unroll
        for (int r = 0; r < 4; ++r) pk.u[r] = f2bf(acc[mt][nt][r]);
        *(uint2*)(Vt + (size_t)ng * (4 * SEQ) + mg) = pk.v;
      }
  }
}

// ---------------- GEMM 2: out = (ctxS @ Wo) * rowscale ----------------

__global__ __launch_bounds__(512, 2) void gemm_out_k(const unsigned short* __restrict__ Cs,
                                                     const unsigned short* __restrict__ WoT,
                                                     float* __restrict__ out) {
  __shared__ char lds[131072];
  const int nwg = 256;  // 64 m-tiles * 4 n-tiles
  const int wg = blockIdx.x;
  const int swz = (wg & 7) * (nwg >> 3) + (wg >> 3);
  const int mtile = swz >> 2, ntile = swz & 3;
  const int m0 = mtile * 256, n0 = ntile * 256;
  const int tid = threadIdx.x;

  f32x4 acc[8][4] = {};
  gemm256_core(Cs, WoT, m0, n0, lds, acc, tid);

  const int lane = tid & 63, w = tid >> 6;
  const int wm = w >> 2, wn = w & 3;
  const int l15 = lane & 15, g = lane >> 4;
  const int mg0 = m0 + wm * 128;
  const int ng0 = n0 + wn * 64;
#pragma unroll
  for (int mt = 0; mt < 8; ++mt)
#pragma unroll
    for (int nt = 0; nt < 4; ++nt) {
      int ng = ng0 + nt * 16 + l15;
      int mg = mg0 + mt * 16 + g * 4;
#pragma unroll
      for (int r = 0; r < 4; ++r) {
        int m = mg + r;
        int s = m & (SEQ - 1);
        // count = 1 at edges (s<128 or s>=3968), else 2; 1e-8 vanishes in fp32
        float scl = (s < 128 || s >= SEQ - 128) ? 1.0f : 0.5f;
        out[(size_t)m * DIM + ng] = acc[mt][nt][r] * scl;
      }
    }
}

// ---------------- attention: swapped-operand flash, no P/Q LDS ----------------
// One block per (b, window, head), 4 waves, wave w owns q-rows [w*64, w*64+64).
// QK^T swapped: S^T = mfma(A=K, B=Q)  -> lane holds q = lane&15, k = 16*kt + g*4 + r.
// PV swapped:  ctx^T = mfma(A=V^T, B=P^T) with permuted contraction order
//   pos (g*8+j) -> k = c*32 + (j>>2)*16 + g*4 + (j&3)
// so the P fragment is the lane's OWN 16 probabilities (no cross-lane moves).

__global__ __launch_bounds__(256, 2) void attn_k(const unsigned short* __restrict__ Qb,
                                                 const unsigned short* __restrict__ Kb,
                                                 const unsigned short* __restrict__ Vt,
                                                 unsigned short* __restrict__ ctxA,
                                                 unsigned short* __restrict__ ctxB) {
  __shared__ unsigned short K_lds[256 * 64];   // 32 KB [256 k-rows][64 d] swizzled
  __shared__ unsigned short V_lds[64 * 256];   // 32 KB [64 d-rows][256 k] swizzled

  const int bid = blockIdx.x;
  const int h = bid & 15;
  const int rem = bid >> 4;
  const int n = rem % NWIN;
  const int b = rem / NWIN;
  const int tid = threadIdx.x;
  const int lane = tid & 63;
  const int w = tid >> 6;
  const int l15 = lane & 15;
  const int g = lane >> 4;

  char* Kc = (char*)K_lds;
  char* Vc = (char*)V_lds;

  const size_t qkbase = ((size_t)b * SEQ + (size_t)n * 128) * DIM + h * 64;

  // ---- stage K (rowbytes 128, 8 rows per wave-op, 16B chunk ^= row&7) ----
  {
    const int srow = lane >> 3, schunk = lane & 7;
    const int sxor8 = (schunk ^ srow) * 8;
    const unsigned short* Kg = Kb + qkbase + (size_t)(w * 64 + srow) * DIM + sxor8;
#pragma unroll
    for (int j = 0; j < 8; ++j)
      gll16(Kg + (size_t)j * 8 * DIM, Kc + (w * 64 + j * 8) * 128);
  }
  // ---- stage V^T (rowbytes 512, 2 rows per wave-op) ----
  {
    const int c = lane & 31, rh = lane >> 5;
#pragma unroll
    for (int j = 0; j < 8; ++j) {
      int r = w * 16 + j * 2 + rh;
      int sx = (c ^ (r & 7)) * 8;
      gll16(Vt + (size_t)(h * 64 + r) * (4 * SEQ) + (size_t)b * SEQ + n * 128 + sx,
            Vc + (w * 16 + j * 2) * 512);
    }
  }

  // ---- Q fragments direct from global (B-operand: q = l15, d = kf*32 + g*8 + j) ----
  bf16x8 qf[4][2];
#pragma unroll
  for (int qt = 0; qt < 4; ++qt)
#pragma unroll
    for (int kf = 0; kf < 2; ++kf)
      qf[qt][kf] = *(const bf16x8*)(Qb + qkbase +
                                    (size_t)(w * 64 + qt * 16 + l15) * DIM + kf * 32 + g * 8);

  __syncthreads();

  f32x4 acc[4][4] = {};   // acc[qt][dt]: ctx^T, q = qt*16+l15, d = dt*16+g*4+r
  float runm[4], runs[4];
#pragma unroll
  for (int i = 0; i < 4; ++i) { runm[i] = -1e30f; runs[i] = 0.f; }
  const float csc = 0.18033688011112042f;  // log2(e)/sqrt(dh)

  for (int kc = 0; kc < 4; ++kc) {
    bf16x8 kfr[4][2];
#pragma unroll
    for (int kt = 0; kt < 4; ++kt) {
      int row = kc * 64 + kt * 16 + l15;
#pragma unroll
      for (int kf = 0; kf < 2; ++kf)
        kfr[kt][kf] = *(const bf16x8*)(Kc + row * 128 + (((kf * 4 + g) ^ (row & 7)) << 4));
    }
    bf16x8 vf[2][4];
#pragma unroll
    for (int c = 0; c < 2; ++c)
#pragma unroll
      for (int dt = 0; dt < 4; ++dt) {
        int row = dt * 16 + l15;
        int c16 = kc * 8 + c * 4 + (g >> 1);
        int off = (g & 1) * 8;
        union { uint2 u2[2]; bf16x8 v; } vv;
        vv.u2[0] = *(const uint2*)(Vc + row * 512 + ((c16 ^ (row & 7)) << 4) + off);
        vv.u2[1] = *(const uint2*)(Vc + row * 512 + (((c16 + 2) ^ (row & 7)) << 4) + off);
        vf[c][dt] = vv.v;
      }

#pragma unroll
    for (int qt = 0; qt < 4; ++qt) {
      f32x4 sc[4] = {};
#pragma unroll
      for (int kt = 0; kt < 4; ++kt)
#pragma unroll
        for (int kf = 0; kf < 2; ++kf)
          sc[kt] = MFMA(kfr[kt][kf], qf[qt][kf], sc[kt]);

      float cm = fmaxf(fmaxf(fmaxf(sc[0][0], sc[0][1]), fmaxf(sc[0][2], sc[0][3])),
                       fmaxf(fmaxf(sc[1][0], sc[1][1]), fmaxf(sc[1][2], sc[1][3])));
      cm = fmaxf(cm, fmaxf(fmaxf(fmaxf(sc[2][0], sc[2][1]), fmaxf(sc[2][2], sc[2][3])),
                           fmaxf(fmaxf(sc[3][0], sc[3][1]), fmaxf(sc[3][2], sc[3][3]))));
      cm = fmaxf(cm, __shfl_xor(cm, 16));
      cm = fmaxf(cm, __shfl_xor(cm, 32));
      float nm = fmaxf(runm[qt], cm);
      float fsc = exp2f((runm[qt] - nm) * csc);
      runm[qt] = nm;
      float ps = 0.f;
#pragma unroll
      for (int kt = 0; kt < 4; ++kt)
#pragma unroll
        for (int r = 0; r < 4; ++r) {
          float p = exp2f((sc[kt][r] - nm) * csc);
          sc[kt][r] = p;
          ps += p;
        }
      ps += __shfl_xor(ps, 16);
      ps += __shfl_xor(ps, 32);
      runs[qt] = runs[qt] * fsc + ps;
#pragma unroll
      for (int dt = 0; dt < 4; ++dt) {
        acc[qt][dt][0] *= fsc; acc[qt][dt][1] *= fsc;
        acc[qt][dt][2] *= fsc; acc[qt][dt][3] *= fsc;
      }
#pragma unroll
      for (int c = 0; c < 2; ++c) {
        union { unsigned u[4]; bf16x8 v; } pa;
        pa.u[0] = pk2bf(sc[2 * c][0], sc[2 * c][1]);
        pa.u[1] = pk2bf(sc[2 * c][2], sc[2 * c][3]);
        pa.u[2] = pk2bf(sc[2 * c + 1][0], sc[2 * c + 1][1]);
        pa.u[3] = pk2bf(sc[2 * c + 1][2], sc[2 * c + 1][3]);
#pragma unroll
        for (int dt = 0; dt < 4; ++dt)
          acc[qt][dt] = MFMA(vf[c][dt], pa.v, acc[qt][dt]);
      }
    }
  }

  unsigned short* outb = (n & 1) ? ctxB : ctxA;
  const size_t obase = ((size_t)b * SEQ + (size_t)n * 128 + w * 64) * DIM + h * 64;
#pragma unroll
  for (int qt = 0; qt < 4; ++qt) {
    float inv = 1.0f / runs[qt];
#pragma unroll
    for (int dt = 0; dt < 4; ++dt) {
      union { unsigned short u[4]; uint2 v; } pk;
#pragma unroll
      for (int r = 0; r < 4; ++r) pk.u[r] = f2bf(acc[qt][dt][r] * inv);
      *(uint2*)(outb + obase + (size_t)(qt * 16 + l15) * DIM + dt * 16 + g * 4) = pk.v;
    }
  }
}

// ---------------- launch ----------------

extern "C" void kernel_launch(void* const* d_in, const int* in_sizes, int n_in,
                              void* d_out, int out_size, void* d_ws, size_t ws_size,
                              hipStream_t stream) {
  const float* X  = (const float*)d_in[0];
  const float* Wq = (const float*)d_in[1];
  const float* Wk = (const float*)d_in[2];
  const float* Wv = (const float*)d_in[3];
  const float* Wo = (const float*)d_in[4];
  float* out = (float*)d_out;

  char* ws = (char*)d_ws;
  const size_t SZ = (size_t)4 * SEQ * DIM * 2;  // 33,554,432 B (one bf16 [16384][1024])
  unsigned short* Xb   = (unsigned short*)(ws);              // also reused as ctxS
  unsigned short* Wt3  = (unsigned short*)(ws + SZ);         // [3072][1024]
  unsigned short* WoT  = (unsigned short*)(ws + SZ + 6291456);
  unsigned short* Qb   = (unsigned short*)(ws + SZ + 8388608);
  unsigned short* Kb   = (unsigned short*)(ws + 2 * SZ + 8388608);
  unsigned short* Vt   = (unsigned short*)(ws + 3 * SZ + 8388608);
  unsigned short* ctxA = (unsigned short*)(ws + 4 * SZ + 8388608);
  unsigned short* ctxB = (unsigned short*)(ws + 5 * SZ + 8388608);
  // total: 6*SZ + 8 MB = 209,715,200 B

  // odd-window buffer rows [0,128) and [3968,4096) are never written -> zero it
  hipMemsetAsync(ctxB, 0, SZ, stream);

  cast_x_k<<<8192, 256, 0, stream>>>(X, Xb);
  tcast_w_k<<<1024, 256, 0, stream>>>(Wq, Wk, Wv, Wo, Wt3, WoT);
  gemm_qkv_k<<<768, 512, 0, stream>>>(Xb, Wt3, Qb, Kb, Vt);
  attn_k<<<4 * NWIN * NHEAD, 256, 0, stream>>>(Qb, Kb, Vt, ctxA, ctxB);
  sum_ctx_k<<<8192, 256, 0, stream>>>(ctxA, ctxB, Xb /* ctxS alias */);
  gemm_out_k<<<256, 512, 0, stream>>>(Xb, WoT, out);
}